// Round 2
// 695.668 us; speedup vs baseline: 1.1164x; 1.1164x over previous
//
#include <hip/hip_runtime.h>
#include <hip/hip_bf16.h>

#define Bb 64
#define Tt 20
#define Ee 512
#define Vv 32000
#define NB 32            // blocks in recurrent kernel

typedef __hip_bfloat16 bf16;
typedef __attribute__((ext_vector_type(8))) short bf16x8;
typedef __attribute__((ext_vector_type(4))) float f32x4;

__device__ __forceinline__ bf16 f2bf(float x) { return __float2bfloat16(x); }

// ---------------------------------------------------------------------------
// Kernel 0: fp32 -> bf16 weight conversion (W_ih / W_hh).
// ---------------------------------------------------------------------------
__global__ void convert_w(const float* __restrict__ src, bf16* __restrict__ dst) {
  int i = blockIdx.x * blockDim.x + threadIdx.x;
  float4 v = ((const float4*)src)[i];
  union { ushort4 u; bf16 h[4]; } pk;
  pk.h[0] = f2bf(v.x); pk.h[1] = f2bf(v.y); pk.h[2] = f2bf(v.z); pk.h[3] = f2bf(v.w);
  ((ushort4*)dst)[i] = pk.u;
}

// ---------------------------------------------------------------------------
// Kernel 1: embedding gather (fp32 -> bf16) + barrier-counter reset.
//  - emb[b,t,:] = bf16(W_emb[captions[b,t], :]);  seq[b,0,:] = emb[b,0,:]
//  - bar[0..31] = 0  (per-step grid-barrier counters, re-zeroed every call)
// ---------------------------------------------------------------------------
__global__ void embed_init(const int* __restrict__ caps, const float* __restrict__ Wemb,
                           bf16* __restrict__ emb, bf16* __restrict__ seq,
                           unsigned int* __restrict__ bar) {
  int row = blockIdx.x;            // b*T + t
  int t = row % Tt;
  int tid = threadIdx.x;           // 0..127
  if (row == 0 && tid < 32) bar[tid] = 0;
  int tok = caps[row];
  float4 v = ((const float4*)(Wemb + (size_t)tok * Ee))[tid];
  union { ushort4 u; bf16 h[4]; } pk;
  pk.h[0] = f2bf(v.x); pk.h[1] = f2bf(v.y); pk.h[2] = f2bf(v.z); pk.h[3] = f2bf(v.w);
  ((ushort4*)(emb + (size_t)row * Ee))[tid] = pk.u;
  if (t == 0) ((ushort4*)(seq + (size_t)row * Ee))[tid] = pk.u;   // row == b*T
}

// ---------------------------------------------------------------------------
// Kernel 2: x-projection, fully parallel (no recurrence):
//   gx[row, col] = emb[row,:] @ W_ih[col,:] + bih[col] + bhh[col]
// row = b*T+t (all 1280), col = gate*512 + j (2048).
// grid = (16 n-tiles, 10 m-tiles), 512 threads. W panel (128x512 bf16, 128KB)
// staged in LDS chunk-layout => conflict-free ds_read_b128.
// ---------------------------------------------------------------------------
__global__ __launch_bounds__(512) void xproj(
    const bf16* __restrict__ A,     // emb [1280,512] bf16
    const bf16* __restrict__ Bw,    // W_ih [2048,512] bf16
    const float* __restrict__ bih, const float* __restrict__ bhh,
    float* __restrict__ gx)         // [1280,2048] fp32
{
  __shared__ __align__(16) bf16 Bs[8][64][16][8];   // 128 KB
  int tid = threadIdx.x;
  int lane = tid & 63;
  int quad = lane >> 4, ln = lane & 15;
  int wid = tid >> 6;
  int wm = wid & 1, wn = wid >> 1;                  // wn 0..3 (32-col slice)
  int n0 = blockIdx.x * 128, m0 = blockIdx.y * 128;

#pragma unroll
  for (int q = 0; q < 16; ++q) {
    int c = q * 512 + tid;          // 0..8191 uint4 chunks
    int r = c >> 6, k8 = c & 63;
    *(uint4*)&Bs[r >> 4][k8][r & 15][0] =
        *(const uint4*)(Bw + (size_t)(n0 + r) * Ee + k8 * 8);
  }
  __syncthreads();

  f32x4 zero = {0.f, 0.f, 0.f, 0.f};
  f32x4 acc[4][2];
#pragma unroll
  for (int mt = 0; mt < 4; ++mt)
#pragma unroll
    for (int nt = 0; nt < 2; ++nt) acc[mt][nt] = zero;

  const bf16* Abase = A + (size_t)(m0 + wm * 64 + ln) * Ee;
#pragma unroll 4
  for (int kk = 0; kk < 16; ++kk) {
    int k = kk * 32 + quad * 8;
    bf16x8 af[4], bfv[2];
#pragma unroll
    for (int mt = 0; mt < 4; ++mt)
      af[mt] = *(const bf16x8*)(Abase + (size_t)mt * 16 * Ee + k);
#pragma unroll
    for (int nt = 0; nt < 2; ++nt)
      bfv[nt] = *(const bf16x8*)&Bs[wn * 2 + nt][kk * 4 + quad][ln][0];
#pragma unroll
    for (int mt = 0; mt < 4; ++mt)
#pragma unroll
      for (int nt = 0; nt < 2; ++nt)
        acc[mt][nt] = __builtin_amdgcn_mfma_f32_16x16x32_bf16(af[mt], bfv[nt], acc[mt][nt], 0, 0, 0);
  }

#pragma unroll
  for (int nt = 0; nt < 2; ++nt) {
    int col = n0 + wn * 32 + nt * 16 + ln;
    float bsum = bih[col] + bhh[col];
#pragma unroll
    for (int mt = 0; mt < 4; ++mt) {
#pragma unroll
      for (int r = 0; r < 4; ++r) {
        int row = m0 + wm * 64 + mt * 16 + quad * 4 + r;
        gx[(size_t)row * (4 * Ee) + col] = acc[mt][nt][r] + bsum;
      }
    }
  }
}

// ---------------------------------------------------------------------------
// Kernel 3: recurrent part, ALL 19 steps in one plain launch. grid = 32
// blocks (one 16-wide j-slice each) x 256 threads (wave g = gate g).
//  - W_hh slice (4 gates x 16 rows x 512 k = 64 KB) LDS-resident across steps.
//  - x-gates+biases pre-folded in gx; cell state c in registers.
//  - h round-trips through seq (bf16); manual device-scope grid barrier
//    (per-step counters; 32 blocks <= 256 CUs => co-resident by capacity).
//  - t=1 skips the GEMM entirely (h0 == 0).
// ---------------------------------------------------------------------------
__global__ __launch_bounds__(256) void lstm_rec(
    const float* __restrict__ gx,   // [1280, 2048]
    bf16* __restrict__ seq,         // [B,T,E]
    const float* __restrict__ feats,
    const bf16* __restrict__ Whh,   // [2048,512] bf16
    unsigned int* __restrict__ bar)
{
  const long XS = (long)Tt * Ee;
  __shared__ __align__(16) bf16 wl[4][64][16][8];   // 64 KB W_hh slice
  __shared__ float gsm[4][64][17];                  // 17.4 KB, padded

  int tid = threadIdx.x;
  int g = tid >> 6;                 // wave id == gate id (0=i,1=f,2=g,3=o)
  int lane = tid & 63;
  int quad = lane >> 4, ln = lane & 15;
  int j0 = blockIdx.x * 16;

  // stage W_hh slice (once): 4096 uint4 chunks, each wave reads full 1KB rows
#pragma unroll
  for (int q = 0; q < 16; ++q) {
    int c = q * 256 + tid;
    int row = c >> 6, k8 = c & 63;
    int gg = row >> 4, rr = row & 15;
    *(uint4*)&wl[gg][k8][rr][0] =
        *(const uint4*)(Whh + ((size_t)gg * Ee + j0 + rr) * Ee + k8 * 8);
  }

  // cell state in registers: c0 = features
  float creg[4];
#pragma unroll
  for (int it = 0; it < 4; ++it) {
    int p = tid + it * 256;
    creg[it] = feats[(p >> 4) * Ee + j0 + (p & 15)];
  }
  __syncthreads();

  for (int t = 1; t < Tt; ++t) {
    if (t > 1) {
      const bf16* hb = seq + (size_t)(t - 1) * Ee;   // h_{t-1}
      f32x4 zero = {0.f, 0.f, 0.f, 0.f};
      f32x4 acc[4];
#pragma unroll
      for (int mt = 0; mt < 4; ++mt) acc[mt] = zero;
#pragma unroll 4
      for (int kk = 0; kk < 16; ++kk) {
        int k = kk * 32 + quad * 8;
        bf16x8 bfrag = *(const bf16x8*)&wl[g][kk * 4 + quad][ln][0];
#pragma unroll
        for (int mt = 0; mt < 4; ++mt) {
          bf16x8 afrag = *(const bf16x8*)(hb + (size_t)(mt * 16 + ln) * XS + k);
          acc[mt] = __builtin_amdgcn_mfma_f32_16x16x32_bf16(afrag, bfrag, acc[mt], 0, 0, 0);
        }
      }
#pragma unroll
      for (int mt = 0; mt < 4; ++mt)
#pragma unroll
        for (int r = 0; r < 4; ++r)
          gsm[g][mt * 16 + quad * 4 + r][ln] = acc[mt][r];
    }
    __syncthreads();

    // pointwise: 1024 (b,j) pairs, 4 per thread
#pragma unroll
    for (int it = 0; it < 4; ++it) {
      int p = tid + it * 256;
      int b = p >> 4, jl = p & 15;
      const float* grow = gx + ((size_t)b * Tt + (t - 1)) * (4 * Ee) + j0 + jl;
      float iv = grow[0];
      float fv = grow[Ee];
      float gv = grow[2 * Ee];
      float ov = grow[3 * Ee];
      if (t > 1) {
        iv += gsm[0][b][jl];
        fv += gsm[1][b][jl];
        gv += gsm[2][b][jl];
        ov += gsm[3][b][jl];
      }
      iv = 1.f / (1.f + __expf(-iv));
      fv = 1.f / (1.f + __expf(-fv));
      ov = 1.f / (1.f + __expf(-ov));
      gv = tanhf(gv);
      creg[it] = fv * creg[it] + iv * gv;
      float hv = ov * tanhf(creg[it]);
      seq[(size_t)b * XS + (size_t)t * Ee + j0 + jl] = f2bf(hv);
    }

    if (t < Tt - 1) {
      // manual grid barrier: release h, count to NB on per-step counter
      __threadfence();
      __syncthreads();
      if (tid == 0) {
        __hip_atomic_fetch_add(&bar[t], 1u, __ATOMIC_ACQ_REL, __HIP_MEMORY_SCOPE_AGENT);
        while (__hip_atomic_load(&bar[t], __ATOMIC_ACQUIRE, __HIP_MEMORY_SCOPE_AGENT) < NB)
          __builtin_amdgcn_s_sleep(2);
      }
      __syncthreads();
      __threadfence();
    }
  }
}

// ---------------------------------------------------------------------------
// Kernel 4: logits = seq[1280,512](bf16) @ W_out[32000,512](fp32)^T + b_out.
// One block per 128-col N-tile (grid = 250), 512 threads. Full 128x512 W
// panel staged in LDS once (fp32->bf16, 128 KB); block loops over all 10
// M-tiles reading A straight from global (L2-resident). W_out fetched from
// HBM exactly once; main loop barrier-free.
// ---------------------------------------------------------------------------
__global__ __launch_bounds__(512) void out_gemm(
    const bf16* __restrict__ A,     // [1280,512] bf16
    const float* __restrict__ Bw,   // [32000,512] fp32
    const float* __restrict__ bias,
    float* __restrict__ Cb)
{
  __shared__ __align__(16) bf16 Bs[8][64][16][8];   // 128 KB
  int tid = threadIdx.x;
  int lane = tid & 63;
  int quad = lane >> 4, ln = lane & 15;
  int wid = tid >> 6;
  int wm = wid & 1, wn = wid >> 1;                  // wn 0..3 (32-col slice)
  int n0 = blockIdx.x * 128;

  // stage W panel (fp32 -> bf16), coalesced float4 reads
#pragma unroll
  for (int q = 0; q < 16; ++q) {
    int c = q * 512 + tid;          // 0..8191 uint4 chunks
    int r = c >> 6, k8 = c & 63;
    const float* src = Bw + (size_t)(n0 + r) * Ee + k8 * 8;
    float4 f0 = *(const float4*)src;
    float4 f1 = *(const float4*)(src + 4);
    union { uint4 u; bf16 h[8]; } pk;
    pk.h[0] = f2bf(f0.x); pk.h[1] = f2bf(f0.y); pk.h[2] = f2bf(f0.z); pk.h[3] = f2bf(f0.w);
    pk.h[4] = f2bf(f1.x); pk.h[5] = f2bf(f1.y); pk.h[6] = f2bf(f1.z); pk.h[7] = f2bf(f1.w);
    *(uint4*)&Bs[r >> 4][k8][r & 15][0] = pk.u;
  }
  __syncthreads();

  float bv[2];
#pragma unroll
  for (int nt = 0; nt < 2; ++nt) bv[nt] = bias[n0 + wn * 32 + nt * 16 + ln];

  for (int m0 = 0; m0 < Bb * Tt; m0 += 128) {
    f32x4 zero = {0.f, 0.f, 0.f, 0.f};
    f32x4 acc[4][2];
#pragma unroll
    for (int mt = 0; mt < 4; ++mt)
#pragma unroll
      for (int nt = 0; nt < 2; ++nt) acc[mt][nt] = zero;

    const bf16* Abase = A + (size_t)(m0 + wm * 64 + ln) * Ee;
#pragma unroll 4
    for (int kk = 0; kk < 16; ++kk) {
      int k = kk * 32 + quad * 8;
      bf16x8 af[4], bfv[2];
#pragma unroll
      for (int mt = 0; mt < 4; ++mt)
        af[mt] = *(const bf16x8*)(Abase + (size_t)mt * 16 * Ee + k);
#pragma unroll
      for (int nt = 0; nt < 2; ++nt)
        bfv[nt] = *(const bf16x8*)&Bs[wn * 2 + nt][kk * 4 + quad][ln][0];
#pragma unroll
      for (int mt = 0; mt < 4; ++mt)
#pragma unroll
        for (int nt = 0; nt < 2; ++nt)
          acc[mt][nt] = __builtin_amdgcn_mfma_f32_16x16x32_bf16(af[mt], bfv[nt], acc[mt][nt], 0, 0, 0);
    }

    // epilogue: + bias, fp32 store. D: col = lane&15, row = quad*4 + reg.
#pragma unroll
    for (int mt = 0; mt < 4; ++mt) {
#pragma unroll
      for (int nt = 0; nt < 2; ++nt) {
        int col = n0 + wn * 32 + nt * 16 + ln;
#pragma unroll
        for (int r = 0; r < 4; ++r) {
          int row = m0 + wm * 64 + mt * 16 + quad * 4 + r;
          Cb[(size_t)row * Vv + col] = acc[mt][nt][r] + bv[nt];
        }
      }
    }
  }
}

// ---------------------------------------------------------------------------
extern "C" void kernel_launch(void* const* d_in, const int* in_sizes, int n_in,
                              void* d_out, int out_size, void* d_ws, size_t ws_size,
                              hipStream_t stream) {
  (void)in_sizes; (void)n_in; (void)out_size; (void)ws_size;
  const float* feats = (const float*)d_in[0];
  const int*   caps  = (const int*)d_in[1];
  const float* Wemb  = (const float*)d_in[2];
  const float* Wout  = (const float*)d_in[3];
  const float* bout  = (const float*)d_in[4];
  const float* Wih   = (const float*)d_in[5];
  const float* Whh   = (const float*)d_in[6];
  const float* bih   = (const float*)d_in[7];
  const float* bhh   = (const float*)d_in[8];
  float* out = (float*)d_out;

  // workspace layout (16B-aligned), ~17.3 MB total:
  bf16* emb    = (bf16*)d_ws;                          // [B,T,E]     1.31 MB
  bf16* seq    = emb   + (size_t)Bb * Tt * Ee;         // [B,T,E]     1.31 MB
  bf16* Wih_b  = seq   + (size_t)Bb * Tt * Ee;         // [4E,E]      2 MB
  bf16* Whh_b  = Wih_b + (size_t)4 * Ee * Ee;          // [4E,E]      2 MB
  float* gx    = (float*)(Whh_b + (size_t)4 * Ee * Ee);// [B*T,4E]    10.5 MB
  unsigned int* bar = (unsigned int*)(gx + (size_t)Bb * Tt * 4 * Ee); // 128 B

  const int WN4 = (4 * Ee * Ee) / 4;                   // float4s per weight matrix
  convert_w<<<WN4 / 256, 256, 0, stream>>>(Wih, Wih_b);
  convert_w<<<WN4 / 256, 256, 0, stream>>>(Whh, Whh_b);
  embed_init<<<Bb * Tt, 128, 0, stream>>>(caps, Wemb, emb, seq, bar);
  xproj<<<dim3(16, 10), 512, 0, stream>>>(emb, Wih_b, bih, bhh, gx);
  lstm_rec<<<NB, 256, 0, stream>>>(gx, seq, feats, Whh_b, bar);
  out_gemm<<<dim3(Vv / 128), 512, 0, stream>>>(seq, Wout, bout, out);
}

// Round 3
// 627.336 us; speedup vs baseline: 1.2380x; 1.1089x over previous
//
#include <hip/hip_runtime.h>
#include <hip/hip_bf16.h>

#define Bb 64
#define Tt 20
#define Ee 512
#define Vv 32000
#define NB 32            // blocks in recurrent kernel

typedef __hip_bfloat16 bf16;
typedef __attribute__((ext_vector_type(8))) short bf16x8;
typedef __attribute__((ext_vector_type(4))) float f32x4;

__device__ __forceinline__ bf16 f2bf(float x) { return __float2bfloat16(x); }

// ---------------------------------------------------------------------------
// Kernel 0: fp32 -> bf16 weight conversion (W_ih / W_hh).
// ---------------------------------------------------------------------------
__global__ void convert_w(const float* __restrict__ src, bf16* __restrict__ dst) {
  int i = blockIdx.x * blockDim.x + threadIdx.x;
  float4 v = ((const float4*)src)[i];
  union { ushort4 u; bf16 h[4]; } pk;
  pk.h[0] = f2bf(v.x); pk.h[1] = f2bf(v.y); pk.h[2] = f2bf(v.z); pk.h[3] = f2bf(v.w);
  ((ushort4*)dst)[i] = pk.u;
}

// ---------------------------------------------------------------------------
// Kernel 1: embedding gather (fp32 -> bf16) + barrier-counter reset.
//  - emb[b,t,:] = bf16(W_emb[captions[b,t], :]);  seq[b,0,:] = emb[b,0,:]
//  - bar[0..31] = 0  (per-step grid-barrier counters, re-zeroed every call)
// ---------------------------------------------------------------------------
__global__ void embed_init(const int* __restrict__ caps, const float* __restrict__ Wemb,
                           bf16* __restrict__ emb, bf16* __restrict__ seq,
                           unsigned int* __restrict__ bar) {
  int row = blockIdx.x;            // b*T + t
  int t = row % Tt;
  int tid = threadIdx.x;           // 0..127
  if (row == 0 && tid < 32) bar[tid] = 0;
  int tok = caps[row];
  float4 v = ((const float4*)(Wemb + (size_t)tok * Ee))[tid];
  union { ushort4 u; bf16 h[4]; } pk;
  pk.h[0] = f2bf(v.x); pk.h[1] = f2bf(v.y); pk.h[2] = f2bf(v.z); pk.h[3] = f2bf(v.w);
  ((ushort4*)(emb + (size_t)row * Ee))[tid] = pk.u;
  if (t == 0) ((ushort4*)(seq + (size_t)row * Ee))[tid] = pk.u;   // row == b*T
}

// ---------------------------------------------------------------------------
// Kernel 2: x-projection, fully parallel (no recurrence):
//   gx[row, col] = emb[row,:] @ W_ih[col,:] + bih[col] + bhh[col]
// ---------------------------------------------------------------------------
__global__ __launch_bounds__(512) void xproj(
    const bf16* __restrict__ A,     // emb [1280,512] bf16
    const bf16* __restrict__ Bw,    // W_ih [2048,512] bf16
    const float* __restrict__ bih, const float* __restrict__ bhh,
    float* __restrict__ gx)         // [1280,2048] fp32
{
  __shared__ __align__(16) bf16 Bs[8][64][16][8];   // 128 KB
  int tid = threadIdx.x;
  int lane = tid & 63;
  int quad = lane >> 4, ln = lane & 15;
  int wid = tid >> 6;
  int wm = wid & 1, wn = wid >> 1;                  // wn 0..3 (32-col slice)
  int n0 = blockIdx.x * 128, m0 = blockIdx.y * 128;

#pragma unroll
  for (int q = 0; q < 16; ++q) {
    int c = q * 512 + tid;          // 0..8191 uint4 chunks
    int r = c >> 6, k8 = c & 63;
    *(uint4*)&Bs[r >> 4][k8][r & 15][0] =
        *(const uint4*)(Bw + (size_t)(n0 + r) * Ee + k8 * 8);
  }
  __syncthreads();

  f32x4 zero = {0.f, 0.f, 0.f, 0.f};
  f32x4 acc[4][2];
#pragma unroll
  for (int mt = 0; mt < 4; ++mt)
#pragma unroll
    for (int nt = 0; nt < 2; ++nt) acc[mt][nt] = zero;

  const bf16* Abase = A + (size_t)(m0 + wm * 64 + ln) * Ee;
#pragma unroll 4
  for (int kk = 0; kk < 16; ++kk) {
    int k = kk * 32 + quad * 8;
    bf16x8 af[4], bfv[2];
#pragma unroll
    for (int mt = 0; mt < 4; ++mt)
      af[mt] = *(const bf16x8*)(Abase + (size_t)mt * 16 * Ee + k);
#pragma unroll
    for (int nt = 0; nt < 2; ++nt)
      bfv[nt] = *(const bf16x8*)&Bs[wn * 2 + nt][kk * 4 + quad][ln][0];
#pragma unroll
    for (int mt = 0; mt < 4; ++mt)
#pragma unroll
      for (int nt = 0; nt < 2; ++nt)
        acc[mt][nt] = __builtin_amdgcn_mfma_f32_16x16x32_bf16(af[mt], bfv[nt], acc[mt][nt], 0, 0, 0);
  }

#pragma unroll
  for (int nt = 0; nt < 2; ++nt) {
    int col = n0 + wn * 32 + nt * 16 + ln;
    float bsum = bih[col] + bhh[col];
#pragma unroll
    for (int mt = 0; mt < 4; ++mt) {
#pragma unroll
      for (int r = 0; r < 4; ++r) {
        int row = m0 + wm * 64 + mt * 16 + quad * 4 + r;
        gx[(size_t)row * (4 * Ee) + col] = acc[mt][nt][r] + bsum;
      }
    }
  }
}

// ---------------------------------------------------------------------------
// Kernel 3: recurrent part, ALL 19 steps in one plain launch. grid = 32
// blocks (one 16-wide j-slice each) x 256 threads (wave g = gate g).
//  - W_hh slice LDS-resident; x-gates+biases pre-folded in gx; c in regs.
//  - gx for the NEXT step prefetched into REGISTERS before the barrier, so
//    the acquire-invalidate can't chill it (only h loads stay cold).
//  - Lean grid barrier: syncthreads (drains stores) -> leader RELEASE
//    fetch_add (one wbL2) -> RELAXED poll (no cache ops) -> one ACQUIRE
//    load (one invL2) -> syncthreads. No __threadfence().
// ---------------------------------------------------------------------------
__global__ __launch_bounds__(256) void lstm_rec(
    const float* __restrict__ gx,   // [1280, 2048]
    bf16* __restrict__ seq,         // [B,T,E]
    const float* __restrict__ feats,
    const bf16* __restrict__ Whh,   // [2048,512] bf16
    unsigned int* __restrict__ bar)
{
  const long XS = (long)Tt * Ee;
  __shared__ __align__(16) bf16 wl[4][64][16][8];   // 64 KB W_hh slice
  __shared__ float gsm[4][64][17];                  // 17.4 KB, padded

  int tid = threadIdx.x;
  int g = tid >> 6;                 // wave id == gate id (0=i,1=f,2=g,3=o)
  int lane = tid & 63;
  int quad = lane >> 4, ln = lane & 15;
  int j0 = blockIdx.x * 16;

  // stage W_hh slice (once)
#pragma unroll
  for (int q = 0; q < 16; ++q) {
    int c = q * 256 + tid;
    int row = c >> 6, k8 = c & 63;
    int gg = row >> 4, rr = row & 15;
    *(uint4*)&wl[gg][k8][rr][0] =
        *(const uint4*)(Whh + ((size_t)gg * Ee + j0 + rr) * Ee + k8 * 8);
  }

  // cell state in registers: c0 = features; gx base pointers per (it)
  float creg[4];
  const float* gxb[4];
#pragma unroll
  for (int it = 0; it < 4; ++it) {
    int p = tid + it * 256;
    int b = p >> 4, jl = p & 15;
    creg[it] = feats[b * Ee + j0 + jl];
    gxb[it] = gx + (size_t)b * Tt * (4 * Ee) + j0 + jl;
  }

  // prefetch gx for step t=1 into registers
  float pre[4][4];
#pragma unroll
  for (int it = 0; it < 4; ++it)
#pragma unroll
    for (int gg = 0; gg < 4; ++gg) pre[it][gg] = gxb[it][gg * Ee];
  __syncthreads();

  for (int t = 1; t < Tt; ++t) {
    if (t > 1) {
      const bf16* hb = seq + (size_t)(t - 1) * Ee;   // h_{t-1}
      f32x4 zero = {0.f, 0.f, 0.f, 0.f};
      f32x4 acc[4];
#pragma unroll
      for (int mt = 0; mt < 4; ++mt) acc[mt] = zero;
#pragma unroll 4
      for (int kk = 0; kk < 16; ++kk) {
        int k = kk * 32 + quad * 8;
        bf16x8 bfrag = *(const bf16x8*)&wl[g][kk * 4 + quad][ln][0];
#pragma unroll
        for (int mt = 0; mt < 4; ++mt) {
          bf16x8 afrag = *(const bf16x8*)(hb + (size_t)(mt * 16 + ln) * XS + k);
          acc[mt] = __builtin_amdgcn_mfma_f32_16x16x32_bf16(afrag, bfrag, acc[mt], 0, 0, 0);
        }
      }
#pragma unroll
      for (int mt = 0; mt < 4; ++mt)
#pragma unroll
        for (int r = 0; r < 4; ++r)
          gsm[g][mt * 16 + quad * 4 + r][ln] = acc[mt][r];
    }
    __syncthreads();

    // pointwise: 1024 (b,j) pairs, 4 per thread; gx already in registers
#pragma unroll
    for (int it = 0; it < 4; ++it) {
      int p = tid + it * 256;
      int b = p >> 4, jl = p & 15;
      float iv = pre[it][0];
      float fv = pre[it][1];
      float gv = pre[it][2];
      float ov = pre[it][3];
      if (t > 1) {
        iv += gsm[0][b][jl];
        fv += gsm[1][b][jl];
        gv += gsm[2][b][jl];
        ov += gsm[3][b][jl];
      }
      iv = 1.f / (1.f + __expf(-iv));
      fv = 1.f / (1.f + __expf(-fv));
      ov = 1.f / (1.f + __expf(-ov));
      gv = tanhf(gv);
      creg[it] = fv * creg[it] + iv * gv;
      float hv = ov * tanhf(creg[it]);
      seq[(size_t)b * XS + (size_t)t * Ee + j0 + jl] = f2bf(hv);
    }

    if (t < Tt - 1) {
      // prefetch gx for step t+1 (independent of h; lands in regs pre-inv)
#pragma unroll
      for (int it = 0; it < 4; ++it)
#pragma unroll
        for (int gg = 0; gg < 4; ++gg)
          pre[it][gg] = gxb[it][(size_t)t * (4 * Ee) + gg * Ee];

      __syncthreads();   // drains all waves' h stores (vmcnt0) before arrive
      if (tid == 0) {
        __hip_atomic_fetch_add(&bar[t], 1u, __ATOMIC_RELEASE, __HIP_MEMORY_SCOPE_AGENT);
        while (__hip_atomic_load(&bar[t], __ATOMIC_RELAXED, __HIP_MEMORY_SCOPE_AGENT) < NB)
          __builtin_amdgcn_s_sleep(1);
        (void)__hip_atomic_load(&bar[t], __ATOMIC_ACQUIRE, __HIP_MEMORY_SCOPE_AGENT);
      }
      __syncthreads();
    }
  }
}

// ---------------------------------------------------------------------------
// Kernel 4: logits = seq[1280,512](bf16) @ W_out[32000,512](fp32)^T + b_out.
// One block per 128-col N-tile (grid = 250), 512 threads; W panel staged in
// LDS once (128 KB); block loops over all 10 M-tiles; W_out fetched from HBM
// exactly once; main loop barrier-free.
// ---------------------------------------------------------------------------
__global__ __launch_bounds__(512) void out_gemm(
    const bf16* __restrict__ A,     // [1280,512] bf16
    const float* __restrict__ Bw,   // [32000,512] fp32
    const float* __restrict__ bias,
    float* __restrict__ Cb)
{
  __shared__ __align__(16) bf16 Bs[8][64][16][8];   // 128 KB
  int tid = threadIdx.x;
  int lane = tid & 63;
  int quad = lane >> 4, ln = lane & 15;
  int wid = tid >> 6;
  int wm = wid & 1, wn = wid >> 1;                  // wn 0..3 (32-col slice)
  int n0 = blockIdx.x * 128;

  // stage W panel (fp32 -> bf16), coalesced float4 reads
#pragma unroll
  for (int q = 0; q < 16; ++q) {
    int c = q * 512 + tid;          // 0..8191 uint4 chunks
    int r = c >> 6, k8 = c & 63;
    const float* src = Bw + (size_t)(n0 + r) * Ee + k8 * 8;
    float4 f0 = *(const float4*)src;
    float4 f1 = *(const float4*)(src + 4);
    union { uint4 u; bf16 h[8]; } pk;
    pk.h[0] = f2bf(f0.x); pk.h[1] = f2bf(f0.y); pk.h[2] = f2bf(f0.z); pk.h[3] = f2bf(f0.w);
    pk.h[4] = f2bf(f1.x); pk.h[5] = f2bf(f1.y); pk.h[6] = f2bf(f1.z); pk.h[7] = f2bf(f1.w);
    *(uint4*)&Bs[r >> 4][k8][r & 15][0] = pk.u;
  }
  __syncthreads();

  float bv[2];
#pragma unroll
  for (int nt = 0; nt < 2; ++nt) bv[nt] = bias[n0 + wn * 32 + nt * 16 + ln];

  for (int m0 = 0; m0 < Bb * Tt; m0 += 128) {
    f32x4 zero = {0.f, 0.f, 0.f, 0.f};
    f32x4 acc[4][2];
#pragma unroll
    for (int mt = 0; mt < 4; ++mt)
#pragma unroll
      for (int nt = 0; nt < 2; ++nt) acc[mt][nt] = zero;

    const bf16* Abase = A + (size_t)(m0 + wm * 64 + ln) * Ee;
#pragma unroll 4
    for (int kk = 0; kk < 16; ++kk) {
      int k = kk * 32 + quad * 8;
      bf16x8 af[4], bfv[2];
#pragma unroll
      for (int mt = 0; mt < 4; ++mt)
        af[mt] = *(const bf16x8*)(Abase + (size_t)mt * 16 * Ee + k);
#pragma unroll
      for (int nt = 0; nt < 2; ++nt)
        bfv[nt] = *(const bf16x8*)&Bs[wn * 2 + nt][kk * 4 + quad][ln][0];
#pragma unroll
      for (int mt = 0; mt < 4; ++mt)
#pragma unroll
        for (int nt = 0; nt < 2; ++nt)
          acc[mt][nt] = __builtin_amdgcn_mfma_f32_16x16x32_bf16(af[mt], bfv[nt], acc[mt][nt], 0, 0, 0);
    }

    // epilogue: + bias, fp32 store. D: col = lane&15, row = quad*4 + reg.
#pragma unroll
    for (int mt = 0; mt < 4; ++mt) {
#pragma unroll
      for (int nt = 0; nt < 2; ++nt) {
        int col = n0 + wn * 32 + nt * 16 + ln;
#pragma unroll
        for (int r = 0; r < 4; ++r) {
          int row = m0 + wm * 64 + mt * 16 + quad * 4 + r;
          Cb[(size_t)row * Vv + col] = acc[mt][nt][r] + bv[nt];
        }
      }
    }
  }
}

// ---------------------------------------------------------------------------
extern "C" void kernel_launch(void* const* d_in, const int* in_sizes, int n_in,
                              void* d_out, int out_size, void* d_ws, size_t ws_size,
                              hipStream_t stream) {
  (void)in_sizes; (void)n_in; (void)out_size; (void)ws_size;
  const float* feats = (const float*)d_in[0];
  const int*   caps  = (const int*)d_in[1];
  const float* Wemb  = (const float*)d_in[2];
  const float* Wout  = (const float*)d_in[3];
  const float* bout  = (const float*)d_in[4];
  const float* Wih   = (const float*)d_in[5];
  const float* Whh   = (const float*)d_in[6];
  const float* bih   = (const float*)d_in[7];
  const float* bhh   = (const float*)d_in[8];
  float* out = (float*)d_out;

  // workspace layout (16B-aligned), ~17.3 MB total:
  bf16* emb    = (bf16*)d_ws;                          // [B,T,E]     1.31 MB
  bf16* seq    = emb   + (size_t)Bb * Tt * Ee;         // [B,T,E]     1.31 MB
  bf16* Wih_b  = seq   + (size_t)Bb * Tt * Ee;         // [4E,E]      2 MB
  bf16* Whh_b  = Wih_b + (size_t)4 * Ee * Ee;          // [4E,E]      2 MB
  float* gx    = (float*)(Whh_b + (size_t)4 * Ee * Ee);// [B*T,4E]    10.5 MB
  unsigned int* bar = (unsigned int*)(gx + (size_t)Bb * Tt * 4 * Ee); // 128 B

  const int WN4 = (4 * Ee * Ee) / 4;                   // float4s per weight matrix
  convert_w<<<WN4 / 256, 256, 0, stream>>>(Wih, Wih_b);
  convert_w<<<WN4 / 256, 256, 0, stream>>>(Whh, Whh_b);
  embed_init<<<Bb * Tt, 128, 0, stream>>>(caps, Wemb, emb, seq, bar);
  xproj<<<dim3(16, 10), 512, 0, stream>>>(emb, Wih_b, bih, bhh, gx);
  lstm_rec<<<NB, 256, 0, stream>>>(gx, seq, feats, Whh_b, bar);
  out_gemm<<<dim3(Vv / 128), 512, 0, stream>>>(seq, Wout, bout, out);
}